// Round 11
// baseline (693.644 us; speedup 1.0000x reference)
//
#include <hip/hip_runtime.h>

typedef unsigned short u16;
typedef unsigned int u32;
typedef unsigned long long u64;
typedef __attribute__((ext_vector_type(8))) short bf16x8;
typedef __attribute__((ext_vector_type(4))) float f32x4;

#define B2 2
#define T2 2048
#define D2 1024
#define H2 8
#define DH 128
#define KSL 512
#define CH 128
#define NCH 16
#define NBH 16
#define MAGIC 0x13579BDFu

__device__ __forceinline__ float bf2f(u32 h) { union { u32 u; float f; } x; x.u = h << 16; return x.f; }
__device__ __forceinline__ u16 f2bf(float f) {
  union { float f; u32 u; } x; x.f = f;
  return (u16)((x.u + 0x7FFFu + ((x.u >> 16) & 1u)) >> 16);
}
__device__ __forceinline__ u32 pack2(float a, float b) { return (u32)f2bf(a) | ((u32)f2bf(b) << 16); }

// ---------------------------------------------------------------------------
// sc1 (device-coherence-point) accessors — WRITES ONLY (+ tiny atomics).
// Bulk reads cached.  Freshness (v12 audit): bar2's single buffer_inv per
// chunk provides all cross-block freshness; bar1 has no inv.  khat is
// precomputed once (v14).  v15: scan writes its read-output to a PRIVATE ys
// buffer (pure sc1 stores, no RMW); attn is fused into the same launch as
// independent blocks so its compute hides under the scan's latency stalls.
// ---------------------------------------------------------------------------
__device__ __forceinline__ u32 cload32(const void* p) {
  return __hip_atomic_load((u32*)p, __ATOMIC_RELAXED, __HIP_MEMORY_SCOPE_AGENT);
}
__device__ __forceinline__ void cstore32(void* p, u32 v) {
  __hip_atomic_store((u32*)p, v, __ATOMIC_RELAXED, __HIP_MEMORY_SCOPE_AGENT);
}
__device__ __forceinline__ u64 cload64(const void* p) {
  return __hip_atomic_load((u64*)p, __ATOMIC_RELAXED, __HIP_MEMORY_SCOPE_AGENT);
}
__device__ __forceinline__ void cstore64(void* p, u64 v) {
  __hip_atomic_store((u64*)p, v, __ATOMIC_RELAXED, __HIP_MEMORY_SCOPE_AGENT);
}
__device__ __forceinline__ float2 cloadf2(const float* p) {
  union { u64 q; float2 f; } x; x.q = cload64(p); return x.f;
}
__device__ __forceinline__ void cstoref2(float* p, float2 v) {
  union { float2 f; u64 q; } x; x.f = v; cstore64(p, x.q);
}

// ---------------------------------------------------------------------------
// Kernel 1: fused QKV projection (unchanged)
// ---------------------------------------------------------------------------
__global__ __launch_bounds__(256) void qkv_gemm(
    const float* __restrict__ x, const float* __restrict__ w,
    const float* __restrict__ bias, u16* __restrict__ qhb,
    u16* __restrict__ khb, u16* __restrict__ vhb) {
  __shared__ u16 As[128 * 72];
  __shared__ u16 Bs[128 * 72];
  const int tid = threadIdx.x;
  const int lane = tid & 63, wv = tid >> 6;
  const int quad = lane >> 4, l15 = lane & 15;
  const int m0 = blockIdx.y * 128, n0 = blockIdx.x * 128;
  const int wr = wv >> 1, wc = wv & 1;
  f32x4 acc[4][4];
#pragma unroll
  for (int i = 0; i < 4; ++i)
#pragma unroll
    for (int j = 0; j < 4; ++j) acc[i][j] = f32x4{0.f, 0.f, 0.f, 0.f};
  const int f4c = tid & 15, r0 = tid >> 4;
  for (int kt = 0; kt < 16; ++kt) {
#pragma unroll
    for (int i = 0; i < 8; ++i) {
      int row = r0 + i * 16;
      float4 a = *(const float4*)(x + (size_t)(m0 + row) * 1024 + kt * 64 + f4c * 4);
      float4 b = *(const float4*)(w + (size_t)(n0 + row) * 1024 + kt * 64 + f4c * 4);
      *(uint2*)(&As[row * 72 + f4c * 4]) = make_uint2(pack2(a.x, a.y), pack2(a.z, a.w));
      *(uint2*)(&Bs[row * 72 + f4c * 4]) = make_uint2(pack2(b.x, b.y), pack2(b.z, b.w));
    }
    __syncthreads();
#pragma unroll
    for (int ks = 0; ks < 2; ++ks) {
      bf16x8 af[4], bff[4];
#pragma unroll
      for (int rt = 0; rt < 4; ++rt)
        af[rt] = *(const bf16x8*)(&As[(wr * 64 + rt * 16 + l15) * 72 + ks * 32 + quad * 8]);
#pragma unroll
      for (int ct = 0; ct < 4; ++ct)
        bff[ct] = *(const bf16x8*)(&Bs[(wc * 64 + ct * 16 + l15) * 72 + ks * 32 + quad * 8]);
#pragma unroll
      for (int rt = 0; rt < 4; ++rt)
#pragma unroll
        for (int ct = 0; ct < 4; ++ct)
          acc[rt][ct] = __builtin_amdgcn_mfma_f32_16x16x32_bf16(af[rt], bff[ct], acc[rt][ct], 0, 0, 0);
    }
    __syncthreads();
  }
#pragma unroll
  for (int ct = 0; ct < 4; ++ct) {
    int n = n0 + wc * 64 + ct * 16 + l15;
    float bv = bias[n];
    int sec = n >> 10, rr2 = n & 1023, hh = rr2 >> 7, dd = rr2 & 127;
    u16* dst = (sec == 0) ? qhb : (sec == 1) ? khb : vhb;
#pragma unroll
    for (int rt = 0; rt < 4; ++rt)
#pragma unroll
      for (int rg = 0; rg < 4; ++rg) {
        int m = m0 + wr * 64 + rt * 16 + quad * 4 + rg;
        int bb = m >> 11, tt = m & 2047;
        dst[((size_t)(bb * 8 + hh) * T2 + tt) * DH + dd] = f2bf(acc[rt][ct][rg] + bv);
      }
  }
}

// ---------------------------------------------------------------------------
// Kernel 2+3 fused: attn (blocks 0-255) + slot-memory scan (blocks 256-511).
// v15: the only coupling between attn and scan was scan's RMW into yin —
// scan now writes its own ys buffer (out_gemm sums both), so the two are
// fully independent and co-resident: 2 blocks/CU (16 waves, 2x37.4KB LDS,
// <=128 VGPR at (512,2)).  attn's ~50us of compute hides under the scan's
// latency stalls (scan: 23% occupancy, 19% VALU).  attn blocks use 4 active
// waves (identical code to the old attn kernel); waves 4-7 run a barrier-
// matched loop then exit.  No deadlock: attn blocks retire unconditionally;
// the scan's gate needs only the 256 scan blocks, which all fit resident.
// ---------------------------------------------------------------------------
struct ScanArgs {
  const u16* qhb; const u16* khb; const u16* vhb;
  float* yin; float* ys; float* sk; float* sv; u16* skb; u16* khatb;
  u32* cnt; uint4* entries;
  u32* barcnt; u32* bargen; u32* ready;
  const float* sinit; const float* temp;
};

__device__ __forceinline__ void bh_barrier(u32* cnt, u32* gen, bool do_inv) {
  asm volatile("" ::: "memory");
  __syncthreads();           // vmcnt drain: this block's sc1 stores are LLC-visible
  if (threadIdx.x == 0) {
    u32 g = cload32(gen);
    u32 a = __hip_atomic_fetch_add(cnt, 1u, __ATOMIC_RELAXED, __HIP_MEMORY_SCOPE_AGENT);
    if ((a & 15u) == 15u) {
      cstore32(gen, g + 1u);
    } else {
      while (cload32(gen) == g) __builtin_amdgcn_s_sleep(2);
    }
    if (do_inv)
      __builtin_amdgcn_fence(__ATOMIC_ACQUIRE, "agent");  // one buffer_inv per chunk
  }
  __syncthreads();
  asm volatile("" ::: "memory");
}

__device__ __forceinline__ void topk16(const float* rowp, int lane, volatile u64* candw,
                                       float& p_out, u32& idx_out) {
  u32 mono[8];
#pragma unroll
  for (int j = 0; j < 8; ++j) {
    float f = rowp[j * 64 + lane];
    u32 u = __float_as_uint(f);
    mono[j] = ((int)u < 0) ? ~u : (u | 0x80000000u);
  }
  u32 mx = mono[0];
#pragma unroll
  for (int j = 1; j < 8; ++j) mx = max(mx, mono[j]);
  u32 s = mx;
#pragma unroll
  for (int k = 2; k <= 64; k <<= 1) {
#pragma unroll
    for (int j = k >> 1; j > 0; j >>= 1) {
      u32 o = (u32)__shfl_xor((int)s, j);
      bool keep_min = (((lane & k) == 0) == ((lane & j) == 0));
      u32 mn = min(s, o), mxx = max(s, o);
      s = keep_min ? mn : mxx;
    }
  }
  u32 thr = (u32)__shfl((int)s, 48);
  u32 base = 0;
#pragma unroll
  for (int j = 0; j < 8; ++j) {
    bool pred = (mono[j] >= thr);
    u64 mask = __ballot(pred);
    u32 pos = base + (u32)__popcll(mask & ((1ull << lane) - 1ull));
    if (pred && pos < 64u)
      candw[pos] = (((u64)mono[j]) << 32) | (u64)(0xFFFFFFFFu - (u32)(j * 64 + lane));
    base += (u32)__popcll(mask);
  }
  __threadfence_block();
  u32 cntc = base < 64u ? base : 64u;
  u64 key = ((u32)lane < cntc) ? candw[lane] : 0ull;
#pragma unroll
  for (int k = 2; k <= 64; k <<= 1) {
#pragma unroll
    for (int j = k >> 1; j > 0; j >>= 1) {
      u64 o = __shfl_xor(key, j);
      bool keep_min = (((lane & k) == 0) == ((lane & j) == 0));
      u64 mn = key < o ? key : o;
      u64 mxx = key < o ? o : key;
      key = keep_min ? mn : mxx;
    }
  }
  u32 um = (u32)(key >> 32);
  float val = __uint_as_float((um & 0x80000000u) ? (um & 0x7FFFFFFFu) : ~um);
  idx_out = 0xFFFFFFFFu - (u32)(key & 0xFFFFFFFFull);
  float mtop = __shfl(val, 63);
  float e = __expf(val - mtop);
  float ssum = e;
#pragma unroll
  for (int sh = 1; sh < 16; sh <<= 1) ssum += __shfl_xor(ssum, sh);
  p_out = e / ssum;
}

__global__ __launch_bounds__(512, 2) void attn_scan(ScanArgs A) {
  // Shared LDS overlay: max(attn 36864 B, scan 37376 B) = 37376 B.
  __shared__ u64 smem_u64[4672];
  char* smem = (char*)smem_u64;
  const int tid = threadIdx.x;
  const int lane = tid & 63, wv = tid >> 6;
  const int quad = lane >> 4, l15 = lane & 15;

  if (blockIdx.x < 256) {
    // =================== ATTN PATH (4 active waves) ===================
    const int abid = blockIdx.x;
    const int qt = abid & 15, bh = abid >> 4;
    const int t0 = qt * 128;
    const int b = bh >> 3, h = bh & 7;
    int j0 = t0 / 64 - 8; if (j0 < 0) j0 = 0;
    int j1 = t0 / 64 + 1;
    if (tid >= 256) {          // waves 4-7: barrier-match then retire
      for (int jt = j0; jt <= j1; ++jt) { __syncthreads(); __syncthreads(); }
      return;
    }
    u16* Pls = (u16*)smem;                 // 128*72 u16 = 18432 B
    u16* VT  = (u16*)(smem + 18432);       // 128*72 u16 = 18432 B
    f32x4 Oa[2][8];
    float mrow[2][4], lrow[2][4];
#pragma unroll
    for (int rt = 0; rt < 2; ++rt) {
#pragma unroll
      for (int dt = 0; dt < 8; ++dt) Oa[rt][dt] = f32x4{0.f, 0.f, 0.f, 0.f};
#pragma unroll
      for (int rg = 0; rg < 4; ++rg) { mrow[rt][rg] = -1e30f; lrow[rt][rg] = 0.f; }
    }
    const u16* qbase = A.qhb + ((size_t)bh * T2 + t0) * DH;
    for (int jt = j0; jt <= j1; ++jt) {
      int kv0 = jt * 64;
      __syncthreads();
      {
        int r = tid & 63, dq = tid >> 6;
        const u16* vrow = A.vhb + ((size_t)bh * T2 + kv0 + r) * DH + dq * 32;
#pragma unroll
        for (int u = 0; u < 4; ++u) {
          uint4 pv = *(const uint4*)(vrow + u * 8);
          int d0 = dq * 32 + u * 8;
          VT[(d0 + 0) * 72 + r] = (u16)(pv.x); VT[(d0 + 1) * 72 + r] = (u16)(pv.x >> 16);
          VT[(d0 + 2) * 72 + r] = (u16)(pv.y); VT[(d0 + 3) * 72 + r] = (u16)(pv.y >> 16);
          VT[(d0 + 4) * 72 + r] = (u16)(pv.z); VT[(d0 + 5) * 72 + r] = (u16)(pv.z >> 16);
          VT[(d0 + 6) * 72 + r] = (u16)(pv.w); VT[(d0 + 7) * 72 + r] = (u16)(pv.w >> 16);
        }
      }
      f32x4 Sa[2][4];
#pragma unroll
      for (int rt = 0; rt < 2; ++rt)
#pragma unroll
        for (int ct = 0; ct < 4; ++ct) Sa[rt][ct] = f32x4{0.f, 0.f, 0.f, 0.f};
#pragma unroll
      for (int ks = 0; ks < 4; ++ks) {
        bf16x8 a0 = *(const bf16x8*)(qbase + (size_t)(wv * 32 + l15) * DH + ks * 32 + quad * 8);
        bf16x8 a1 = *(const bf16x8*)(qbase + (size_t)(wv * 32 + 16 + l15) * DH + ks * 32 + quad * 8);
#pragma unroll
        for (int ct = 0; ct < 4; ++ct) {
          bf16x8 bb = *(const bf16x8*)(A.khb + ((size_t)bh * T2 + kv0 + ct * 16 + l15) * DH + ks * 32 + quad * 8);
          Sa[0][ct] = __builtin_amdgcn_mfma_f32_16x16x32_bf16(a0, bb, Sa[0][ct], 0, 0, 0);
          Sa[1][ct] = __builtin_amdgcn_mfma_f32_16x16x32_bf16(a1, bb, Sa[1][ct], 0, 0, 0);
        }
      }
#pragma unroll
      for (int rt = 0; rt < 2; ++rt)
#pragma unroll
        for (int rg = 0; rg < 4; ++rg) {
          int row = wv * 32 + rt * 16 + quad * 4 + rg;
          int qp = t0 + row;
          float vals[4];
          float mx = -1e30f;
#pragma unroll
          for (int ct = 0; ct < 4; ++ct) {
            int kp = kv0 + ct * 16 + l15;
            float s = Sa[rt][ct][rg] * 0.08838834764831845f;
            bool ok = (kp <= qp) && (kp + 512 > qp);
            s = ok ? s : -1e30f;
            vals[ct] = s;
            mx = fmaxf(mx, s);
          }
#pragma unroll
          for (int sh = 1; sh < 16; sh <<= 1) mx = fmaxf(mx, __shfl_xor(mx, sh));
          float mold = mrow[rt][rg];
          float mnew = fmaxf(mold, mx);
          float alpha = __expf(mold - mnew);
          float rsum = 0.f;
          float pv_[4];
#pragma unroll
          for (int ct = 0; ct < 4; ++ct) {
            float p = (vals[ct] < -1e29f) ? 0.f : __expf(vals[ct] - mnew);
            pv_[ct] = p; rsum += p;
          }
#pragma unroll
          for (int sh = 1; sh < 16; sh <<= 1) rsum += __shfl_xor(rsum, sh);
          lrow[rt][rg] = lrow[rt][rg] * alpha + rsum;
          mrow[rt][rg] = mnew;
#pragma unroll
          for (int dt = 0; dt < 8; ++dt) Oa[rt][dt][rg] *= alpha;
#pragma unroll
          for (int ct = 0; ct < 4; ++ct) Pls[row * 72 + ct * 16 + l15] = f2bf(pv_[ct]);
        }
      __syncthreads();
#pragma unroll
      for (int ks = 0; ks < 2; ++ks) {
        bf16x8 a0 = *(const bf16x8*)(&Pls[(wv * 32 + l15) * 72 + ks * 32 + quad * 8]);
        bf16x8 a1 = *(const bf16x8*)(&Pls[(wv * 32 + 16 + l15) * 72 + ks * 32 + quad * 8]);
#pragma unroll
        for (int dt = 0; dt < 8; ++dt) {
          bf16x8 bb = *(const bf16x8*)(&VT[(dt * 16 + l15) * 72 + ks * 32 + quad * 8]);
          Oa[0][dt] = __builtin_amdgcn_mfma_f32_16x16x32_bf16(a0, bb, Oa[0][dt], 0, 0, 0);
          Oa[1][dt] = __builtin_amdgcn_mfma_f32_16x16x32_bf16(a1, bb, Oa[1][dt], 0, 0, 0);
        }
      }
    }
#pragma unroll
    for (int rt = 0; rt < 2; ++rt)
#pragma unroll
      for (int rg = 0; rg < 4; ++rg) {
        int row = wv * 32 + rt * 16 + quad * 4 + rg;
        float invl = 1.0f / lrow[rt][rg];
#pragma unroll
        for (int dt = 0; dt < 8; ++dt)
          A.yin[((size_t)b * T2 + t0 + row) * D2 + h * DH + dt * 16 + l15] = Oa[rt][dt][rg] * invl;
      }
    return;
  }

  // =================== SCAN PATH (v14, ys pure-store) ===================
  const int sb = blockIdx.x - 256;
  const int xcd = sb & 7;
  const int wi = sb >> 3;                   // 0..31 within XCD
  const int bh = xcd * 2 + (wi >> 4);       // 2 bh per XCD
  const int blk = wi & 15;                  // 16 blocks per bh
  const int b = bh >> 3, h = bh & 7;
  float* scores_r = (float*)smem;                    // 8*520*4 = 16640 B
  float* scores_w = (float*)(smem + 16640);          // 16640 B
  u64* cand = (u64*)(smem + 33280);                  // 8*64*8 = 4096 B

  const float invtemp = 1.0f / A.temp[0];
  const float sc_r = 0.08838834764831845f * invtemp;

  // ---- init: this block's 32 slots (4 per wave) ----
#pragma unroll 1
  for (int i = 0; i < 4; ++i) {
    int s = blk * 32 + wv * 4 + i;
    float2 v2 = *(const float2*)(A.sinit + (size_t)s * 1024 + h * 128 + lane * 2);
    float ssq = v2.x * v2.x + v2.y * v2.y;
#pragma unroll
    for (int sh = 1; sh < 64; sh <<= 1) ssq += __shfl_xor(ssq, sh);
    float inv = 1.0f / (sqrtf(ssq) + 1e-6f);
    size_t off = ((size_t)bh * KSL + s) * DH + lane * 2;
    cstoref2(A.sk + off, make_float2(v2.x * inv, v2.y * inv));
    cstoref2(A.sv + off, v2);
    cstore32(A.skb + off, pack2(v2.x * inv, v2.y * inv));
    if (lane == 0) cstore32(&A.cnt[bh * KSL + s], 0u);
  }
  // ---- init: khat pre-pass — this wave's row for ALL 16 chunks ----
#pragma unroll 1
  for (int ci = 0; ci < NCH; ++ci) {
    int trow = ci * CH + blk * 8 + wv;
    u32 kraw = *(const u32*)(A.khb + ((size_t)bh * T2 + trow) * DH + lane * 2);
    float k0 = bf2f(kraw & 0xFFFFu), k1 = bf2f(kraw >> 16);
    float ssq = k0 * k0 + k1 * k1;
#pragma unroll
    for (int sh = 1; sh < 64; sh <<= 1) ssq += __shfl_xor(ssq, sh);
    float inv = 1.0f / (sqrtf(ssq) + 1e-6f);
    cstore32(A.khatb + ((size_t)bh * T2 + trow) * DH + lane * 2, pack2(k0 * inv, k1 * inv));
  }
  if (blk == 0 && tid == 0) { cstore32(A.barcnt + bh, 0u); cstore32(A.bargen + bh, 0u); }
  __syncthreads();  // drain vmcnt: init + khat stores LLC-visible before ready publish
  if (tid == 0) {
    cstore32(&A.ready[bh * 16 + blk], MAGIC);
    for (int i = 0; i < 16; ++i)
      while (cload32(&A.ready[bh * 16 + i]) != MAGIC) __builtin_amdgcn_s_sleep(2);
    __builtin_amdgcn_fence(__ATOMIC_ACQUIRE, "agent");  // drop stale lines before first reads
  }
  __syncthreads();

  u32* bcnt = A.barcnt + bh;
  u32* bgen = A.bargen + bh;

#pragma unroll 1
  for (int ci = 0; ci < NCH; ++ci) {
    const int t0base = ci * CH;
    const int c = blk * 8 + wv;          // this wave's chunk-row
    const int trow = t0base + c;
    // ---- A13: fused scores.  A-rows 0-7 = q, 8-15 = khat (khatb, immutable).
    {
      const u16* qbase = A.qhb + ((size_t)bh * T2 + t0base + blk * 8) * DH;
      const u16* hbase = A.khatb + ((size_t)bh * T2 + t0base + blk * 8) * DH;
      const u16* sbase = A.skb + (size_t)bh * KSL * DH;
      f32x4 acc[4];
#pragma unroll
      for (int ct = 0; ct < 4; ++ct) acc[ct] = f32x4{0.f, 0.f, 0.f, 0.f};
#pragma unroll
      for (int ks = 0; ks < 4; ++ks) {
        bf16x8 a;
        if (l15 < 8)
          a = *(const bf16x8*)(qbase + (size_t)l15 * DH + ks * 32 + quad * 8);
        else
          a = *(const bf16x8*)(hbase + (size_t)(l15 - 8) * DH + ks * 32 + quad * 8);
#pragma unroll
        for (int ct = 0; ct < 4; ++ct) {
          bf16x8 bb = *(const bf16x8*)(sbase + (size_t)(wv * 64 + ct * 16 + l15) * DH + ks * 32 + quad * 8);
          acc[ct] = __builtin_amdgcn_mfma_f32_16x16x32_bf16(a, bb, acc[ct], 0, 0, 0);
        }
      }
#pragma unroll
      for (int ct = 0; ct < 4; ++ct)
#pragma unroll
        for (int rg = 0; rg < 4; ++rg) {
          int m = quad * 4 + rg;
          int col = wv * 64 + ct * 16 + l15;
          if (m < 8) scores_r[m * 520 + col] = acc[ct][rg] * sc_r;
          else       scores_w[(m - 8) * 520 + col] = acc[ct][rg];
        }
    }
    __syncthreads();
    // ---- A24: both top-16s; read-gather -> ys (pure store); append entries ----
    {
      float p; u32 sidx;
      topk16(&scores_r[wv * 520], lane, cand + wv * 64, p, sidx);
      float acc0 = 0.f, acc1 = 0.f;
      const float* svb = A.sv + (size_t)bh * KSL * DH;
#pragma unroll
      for (int r = 0; r < 16; ++r) {
        float pr = __shfl(p, 63 - r);
        u32 ir = (u32)__shfl((int)sidx, 63 - r);
        float2 vv = *(const float2*)(svb + (size_t)ir * DH + lane * 2);
        acc0 += pr * vv.x; acc1 += pr * vv.y;
      }
      cstoref2(A.ys + ((size_t)b * T2 + trow) * D2 + h * DH + lane * 2,
               make_float2(acc0, acc1));

      float wp; u32 widx;
      topk16(&scores_w[wv * 520], lane, cand + wv * 64, wp, widx);
      const int r = lane >> 2, g = lane & 3;   // 16 picks x 4 lanes
      float wr = __shfl(wp, 63 - r);
      u32 ir = (u32)__shfl((int)widx, 63 - r);
      const float* kb = A.sk + ((size_t)bh * KSL + ir) * DH + g * 32;
      const u16* vb = A.vhb + ((size_t)bh * T2 + trow) * DH + g * 32;
      float part = 0.f;
#pragma unroll
      for (int u2 = 0; u2 < 4; ++u2) {
        uint4 vvp = *(const uint4*)(vb + u2 * 8);
        float4 k0 = *(const float4*)(kb + u2 * 8);
        float4 k1 = *(const float4*)(kb + u2 * 8 + 4);
        part += bf2f(vvp.x & 0xFFFFu) * k0.x + bf2f(vvp.x >> 16) * k0.y
              + bf2f(vvp.y & 0xFFFFu) * k0.z + bf2f(vvp.y >> 16) * k0.w
              + bf2f(vvp.z & 0xFFFFu) * k1.x + bf2f(vvp.z >> 16) * k1.y
              + bf2f(vvp.w & 0xFFFFu) * k1.z + bf2f(vvp.w >> 16) * k1.w;
      }
      part += __shfl_xor(part, 1);
      part += __shfl_xor(part, 2);
      if (g == 0) {
        u32 pos = __hip_atomic_fetch_add(&A.cnt[bh * KSL + ir], 1u,
                                         __ATOMIC_RELAXED, __HIP_MEMORY_SCOPE_AGENT);
        if (pos < 128u) {
          u32* e = (u32*)(A.entries + ((size_t)bh * KSL + ir) * 128 + pos);
          cstore64(e, (u64)(u32)c | ((u64)__float_as_uint(wr) << 32));
          cstore32(e + 2, __float_as_uint(part));
        }
      }
    }
    bh_barrier(bcnt, bgen, false);   // bar1: NO inv (v12 audit)
    // ---- B: lane-parallel entry fetch + 16-deep batched gathers ----
    {
      u32 n4[4]; size_t soff4[4];
      uint4 eL0[4], eL1[4];
#pragma unroll
      for (int i = 0; i < 4; ++i) {
        soff4[i] = (size_t)bh * KSL + blk * 32 + wv * 4 + i;
        n4[i] = cload32(&A.cnt[soff4[i]]);
        const uint4* eb = A.entries + soff4[i] * 128;
        eL0[i] = eb[lane];         // cached, coalesced; fresh (audit)
        eL1[i] = eb[64 + lane];    // buffer always 128 entries -> no guard needed
      }
#pragma unroll
      for (int i = 0; i < 4; ++i) {
        size_t roff = soff4[i] * DH + lane * 2;
        float2 V = *(const float2*)(A.sv + roff);
        float2 Kr = *(const float2*)(A.sk + roff);
        u32 nd = n4[i] < 128u ? n4[i] : 128u;
        float dv0 = 0, dv1 = 0, dk0 = 0, dk1 = 0;
#pragma unroll 1
        for (u32 b2 = 0; b2 < nd; b2 += 16) {
          u32 m = nd - b2; if (m > 16u) m = 16u;
          u32 sx = (b2 < 64u) ? eL0[i].x : eL1[i].x;
          u32 sy = (b2 < 64u) ? eL0[i].y : eL1[i].y;
          u32 sz = (b2 < 64u) ? eL0[i].z : eL1[i].z;
          u32 vr[16], hr[16];
#pragma unroll
          for (int j = 0; j < 16; ++j) if (j < (int)m) {
            u32 src = (b2 + (u32)j) & 63u;
            u32 c2 = (u32)__shfl((int)sx, (int)src);
            vr[j] = *(const u32*)(A.vhb + ((size_t)bh * T2 + t0base + c2) * DH + lane * 2);
            hr[j] = *(const u32*)(A.khatb + ((size_t)bh * T2 + t0base + c2) * DH + lane * 2);
          }
#pragma unroll
          for (int j = 0; j < 16; ++j) if (j < (int)m) {
            u32 src = (b2 + (u32)j) & 63u;
            float wpe = __uint_as_float((u32)__shfl((int)sy, (int)src));
            float pj = __uint_as_float((u32)__shfl((int)sz, (int)src));
            dv0 += wpe * (bf2f(vr[j] & 0xFFFFu) - pj * Kr.x);
            dv1 += wpe * (bf2f(vr[j] >> 16) - pj * Kr.y);
            dk0 += wpe * (bf2f(hr[j] & 0xFFFFu) - Kr.x);
            dk1 += wpe * (bf2f(hr[j] >> 16) - Kr.y);
          }
        }
        cstoref2(A.sv + roff, make_float2(0.99f * V.x + 0.1f * dv0, 0.99f * V.y + 0.1f * dv1));
        if (n4[i] > 0u) {
          float u0 = Kr.x + 0.1f * dk0, u1 = Kr.y + 0.1f * dk1;
          float ssq = u0 * u0 + u1 * u1;
#pragma unroll
          for (int sh = 1; sh < 64; sh <<= 1) ssq += __shfl_xor(ssq, sh);
          float inv = 1.0f / (sqrtf(ssq) + 1e-6f);
          u0 *= inv; u1 *= inv;
          cstoref2(A.sk + roff, make_float2(u0, u1));
          cstore32(A.skb + roff, pack2(u0, u1));
        }
        if (lane == 0) cstore32(&A.cnt[soff4[i]], 0u);
      }
    }
    bh_barrier(bcnt, bgen, true);    // bar2: the one inv per chunk
  }
}

// ---------------------------------------------------------------------------
// Kernel 4: output projection — stages yin + ys (scan's private read-output)
// ---------------------------------------------------------------------------
__global__ __launch_bounds__(256) void out_gemm(
    const float* __restrict__ yin, const float* __restrict__ ys,
    const float* __restrict__ w,
    const float* __restrict__ bias, float* __restrict__ out) {
  __shared__ u16 As[128 * 72];
  __shared__ u16 Bs[128 * 72];
  const int tid = threadIdx.x;
  const int lane = tid & 63, wv = tid >> 6;
  const int quad = lane >> 4, l15 = lane & 15;
  const int m0 = blockIdx.y * 128, n0 = blockIdx.x * 128;
  const int wr = wv >> 1, wc = wv & 1;
  f32x4 acc[4][4];
#pragma unroll
  for (int i = 0; i < 4; ++i)
#pragma unroll
    for (int j = 0; j < 4; ++j) acc[i][j] = f32x4{0.f, 0.f, 0.f, 0.f};
  const int f4c = tid & 15, r0 = tid >> 4;
  for (int kt = 0; kt < 16; ++kt) {
#pragma unroll
    for (int i = 0; i < 8; ++i) {
      int row = r0 + i * 16;
      size_t aidx = (size_t)(m0 + row) * 1024 + kt * 64 + f4c * 4;
      float4 a = *(const float4*)(yin + aidx);
      float4 a2 = *(const float4*)(ys + aidx);
      a.x += a2.x; a.y += a2.y; a.z += a2.z; a.w += a2.w;
      float4 b = *(const float4*)(w + (size_t)(n0 + row) * 1024 + kt * 64 + f4c * 4);
      *(uint2*)(&As[row * 72 + f4c * 4]) = make_uint2(pack2(a.x, a.y), pack2(a.z, a.w));
      *(uint2*)(&Bs[row * 72 + f4c * 4]) = make_uint2(pack2(b.x, b.y), pack2(b.z, b.w));
    }
    __syncthreads();
#pragma unroll
    for (int ks = 0; ks < 2; ++ks) {
      bf16x8 af[4], bff[4];
#pragma unroll
      for (int rt = 0; rt < 4; ++rt)
        af[rt] = *(const bf16x8*)(&As[(wr * 64 + rt * 16 + l15) * 72 + ks * 32 + quad * 8]);
#pragma unroll
      for (int ct = 0; ct < 4; ++ct)
        bff[ct] = *(const bf16x8*)(&Bs[(wc * 64 + ct * 16 + l15) * 72 + ks * 32 + quad * 8]);
#pragma unroll
      for (int rt = 0; rt < 4; ++rt)
#pragma unroll
        for (int ct = 0; ct < 4; ++ct)
          acc[rt][ct] = __builtin_amdgcn_mfma_f32_16x16x32_bf16(af[rt], bff[ct], acc[rt][ct], 0, 0, 0);
    }
    __syncthreads();
  }
#pragma unroll
  for (int ct = 0; ct < 4; ++ct) {
    int n = n0 + wc * 64 + ct * 16 + l15;
    float bv = bias[n];
#pragma unroll
    for (int rt = 0; rt < 4; ++rt)
#pragma unroll
      for (int rg = 0; rg < 4; ++rg) {
        int m = m0 + wr * 64 + rt * 16 + quad * 4 + rg;
        out[(size_t)m * 1024 + n] = acc[rt][ct][rg] + bv;
      }
  }
}

// ---------------------------------------------------------------------------
extern "C" void kernel_launch(void* const* d_in, const int* in_sizes, int n_in,
                              void* d_out, int out_size, void* d_ws, size_t ws_size,
                              hipStream_t stream) {
  const float* x = (const float*)d_in[0];
  const float* Wqkv = (const float*)d_in[1];
  const float* bqkv = (const float*)d_in[2];
  const float* Wo = (const float*)d_in[3];
  const float* bo = (const float*)d_in[4];
  const float* Sinit = (const float*)d_in[5];
  const float* temp = (const float*)d_in[6];
  float* out = (float*)d_out;

  char* p = (char*)d_ws;
  auto take = [&](size_t bytes) { char* r = p; p += (bytes + 255) & ~(size_t)255; return r; };
  u16* qhb = (u16*)take((size_t)NBH * T2 * DH * 2);
  u16* khb = (u16*)take((size_t)NBH * T2 * DH * 2);
  u16* vhb = (u16*)take((size_t)NBH * T2 * DH * 2);
  float* yin = (float*)take((size_t)B2 * T2 * D2 * 4);
  float* ys = (float*)take((size_t)B2 * T2 * D2 * 4);    // v15: scan's private read-output
  float* sk = (float*)take((size_t)NBH * KSL * DH * 4);
  float* sv = (float*)take((size_t)NBH * KSL * DH * 4);
  u16* skb = (u16*)take((size_t)NBH * KSL * DH * 2);
  u16* khatb = (u16*)take((size_t)NBH * T2 * DH * 2);    // full T2 (v14)
  u32* cnt = (u32*)take((size_t)NBH * KSL * 4);
  uint4* entries = (uint4*)take((size_t)NBH * KSL * 128 * 16);
  u32* barcnt = (u32*)take(64 * 4);
  u32* bargen = (u32*)take(64 * 4);
  u32* ready = (u32*)take(NBH * 16 * 4);

  hipLaunchKernelGGL(qkv_gemm, dim3(24, 32), dim3(256), 0, stream, x, Wqkv, bqkv, qhb, khb, vhb);
  ScanArgs sa{qhb, khb, vhb, yin, ys, sk, sv, skb, khatb, cnt, entries, barcnt, bargen, ready, Sinit, temp};
  hipLaunchKernelGGL(attn_scan, dim3(512), dim3(512), 0, stream, sa);
  hipLaunchKernelGGL(out_gemm, dim3(8, 32), dim3(256), 0, stream, yin, ys, Wo, bo, out);
}

// Round 12
// 676.456 us; speedup vs baseline: 1.0254x; 1.0254x over previous
//
#include <hip/hip_runtime.h>

typedef unsigned short u16;
typedef unsigned int u32;
typedef unsigned long long u64;
typedef __attribute__((ext_vector_type(8))) short bf16x8;
typedef __attribute__((ext_vector_type(4))) float f32x4;

#define B2 2
#define T2 2048
#define D2 1024
#define H2 8
#define DH 128
#define KSL 512
#define CH 128
#define NCH 16
#define NBH 16
#define MAGIC 0x13579BDFu

__device__ __forceinline__ float bf2f(u32 h) { union { u32 u; float f; } x; x.u = h << 16; return x.f; }
__device__ __forceinline__ u16 f2bf(float f) {
  union { float f; u32 u; } x; x.f = f;
  return (u16)((x.u + 0x7FFFu + ((x.u >> 16) & 1u)) >> 16);
}
__device__ __forceinline__ u32 pack2(float a, float b) { return (u32)f2bf(a) | ((u32)f2bf(b) << 16); }

// ---------------------------------------------------------------------------
// sc1 (device-coherence-point) accessors — WRITES ONLY (+ tiny atomics).
// Bulk reads cached.  Freshness (v12 audit, verified): bar2's single
// buffer_inv per chunk provides ALL cross-block freshness; bar1 carries no
// inv.  khat precomputed once into full-T2 khatb (v14, verified).
// v16: A24's two serial topk->round-trip chains fused into ONE dual bitonic
// network + joint gather issue (both index sets ready before any memory op,
// so the sv-gather RT and sk/vhb-dot RT overlap: 2 exposed RTs -> 1).
// ---------------------------------------------------------------------------
__device__ __forceinline__ u32 cload32(const void* p) {
  return __hip_atomic_load((u32*)p, __ATOMIC_RELAXED, __HIP_MEMORY_SCOPE_AGENT);
}
__device__ __forceinline__ void cstore32(void* p, u32 v) {
  __hip_atomic_store((u32*)p, v, __ATOMIC_RELAXED, __HIP_MEMORY_SCOPE_AGENT);
}
__device__ __forceinline__ u64 cload64(const void* p) {
  return __hip_atomic_load((u64*)p, __ATOMIC_RELAXED, __HIP_MEMORY_SCOPE_AGENT);
}
__device__ __forceinline__ void cstore64(void* p, u64 v) {
  __hip_atomic_store((u64*)p, v, __ATOMIC_RELAXED, __HIP_MEMORY_SCOPE_AGENT);
}
__device__ __forceinline__ float2 cloadf2(const float* p) {
  union { u64 q; float2 f; } x; x.q = cload64(p); return x.f;
}
__device__ __forceinline__ void cstoref2(float* p, float2 v) {
  union { float2 f; u64 q; } x; x.f = v; cstore64(p, x.q);
}

// ---------------------------------------------------------------------------
// Kernel 1: fused QKV projection (unchanged)
// ---------------------------------------------------------------------------
__global__ __launch_bounds__(256) void qkv_gemm(
    const float* __restrict__ x, const float* __restrict__ w,
    const float* __restrict__ bias, u16* __restrict__ qhb,
    u16* __restrict__ khb, u16* __restrict__ vhb) {
  __shared__ u16 As[128 * 72];
  __shared__ u16 Bs[128 * 72];
  const int tid = threadIdx.x;
  const int lane = tid & 63, wv = tid >> 6;
  const int quad = lane >> 4, l15 = lane & 15;
  const int m0 = blockIdx.y * 128, n0 = blockIdx.x * 128;
  const int wr = wv >> 1, wc = wv & 1;
  f32x4 acc[4][4];
#pragma unroll
  for (int i = 0; i < 4; ++i)
#pragma unroll
    for (int j = 0; j < 4; ++j) acc[i][j] = f32x4{0.f, 0.f, 0.f, 0.f};
  const int f4c = tid & 15, r0 = tid >> 4;
  for (int kt = 0; kt < 16; ++kt) {
#pragma unroll
    for (int i = 0; i < 8; ++i) {
      int row = r0 + i * 16;
      float4 a = *(const float4*)(x + (size_t)(m0 + row) * 1024 + kt * 64 + f4c * 4);
      float4 b = *(const float4*)(w + (size_t)(n0 + row) * 1024 + kt * 64 + f4c * 4);
      *(uint2*)(&As[row * 72 + f4c * 4]) = make_uint2(pack2(a.x, a.y), pack2(a.z, a.w));
      *(uint2*)(&Bs[row * 72 + f4c * 4]) = make_uint2(pack2(b.x, b.y), pack2(b.z, b.w));
    }
    __syncthreads();
#pragma unroll
    for (int ks = 0; ks < 2; ++ks) {
      bf16x8 af[4], bff[4];
#pragma unroll
      for (int rt = 0; rt < 4; ++rt)
        af[rt] = *(const bf16x8*)(&As[(wr * 64 + rt * 16 + l15) * 72 + ks * 32 + quad * 8]);
#pragma unroll
      for (int ct = 0; ct < 4; ++ct)
        bff[ct] = *(const bf16x8*)(&Bs[(wc * 64 + ct * 16 + l15) * 72 + ks * 32 + quad * 8]);
#pragma unroll
      for (int rt = 0; rt < 4; ++rt)
#pragma unroll
        for (int ct = 0; ct < 4; ++ct)
          acc[rt][ct] = __builtin_amdgcn_mfma_f32_16x16x32_bf16(af[rt], bff[ct], acc[rt][ct], 0, 0, 0);
    }
    __syncthreads();
  }
#pragma unroll
  for (int ct = 0; ct < 4; ++ct) {
    int n = n0 + wc * 64 + ct * 16 + l15;
    float bv = bias[n];
    int sec = n >> 10, rr2 = n & 1023, hh = rr2 >> 7, dd = rr2 & 127;
    u16* dst = (sec == 0) ? qhb : (sec == 1) ? khb : vhb;
#pragma unroll
    for (int rt = 0; rt < 4; ++rt)
#pragma unroll
      for (int rg = 0; rg < 4; ++rg) {
        int m = m0 + wr * 64 + rt * 16 + quad * 4 + rg;
        int bb = m >> 11, tt = m & 2047;
        dst[((size_t)(bb * 8 + hh) * T2 + tt) * DH + dd] = f2bf(acc[rt][ct][rg] + bv);
      }
  }
}

// ---------------------------------------------------------------------------
// Kernel 2: sliding-window attention (unchanged)
// ---------------------------------------------------------------------------
__global__ __launch_bounds__(256) void attn_kernel(
    const u16* __restrict__ qhb, const u16* __restrict__ khb,
    const u16* __restrict__ vhb, float* __restrict__ yin) {
  __shared__ u16 Pls[128 * 72];
  __shared__ u16 VT[128 * 72];
  const int tid = threadIdx.x;
  const int lane = tid & 63, wv = tid >> 6;
  const int quad = lane >> 4, l15 = lane & 15;
  const int bh = blockIdx.y, qt = blockIdx.x;
  const int t0 = qt * 128;
  const int b = bh >> 3, h = bh & 7;
  f32x4 Oa[2][8];
  float mrow[2][4], lrow[2][4];
#pragma unroll
  for (int rt = 0; rt < 2; ++rt) {
#pragma unroll
    for (int dt = 0; dt < 8; ++dt) Oa[rt][dt] = f32x4{0.f, 0.f, 0.f, 0.f};
#pragma unroll
    for (int rg = 0; rg < 4; ++rg) { mrow[rt][rg] = -1e30f; lrow[rt][rg] = 0.f; }
  }
  const u16* qbase = qhb + ((size_t)bh * T2 + t0) * DH;
  int j0 = t0 / 64 - 8; if (j0 < 0) j0 = 0;
  int j1 = t0 / 64 + 1;
  for (int jt = j0; jt <= j1; ++jt) {
    int kv0 = jt * 64;
    __syncthreads();
    {
      int r = tid & 63, dq = tid >> 6;
      const u16* vrow = vhb + ((size_t)bh * T2 + kv0 + r) * DH + dq * 32;
#pragma unroll
      for (int u = 0; u < 4; ++u) {
        uint4 pv = *(const uint4*)(vrow + u * 8);
        int d0 = dq * 32 + u * 8;
        VT[(d0 + 0) * 72 + r] = (u16)(pv.x); VT[(d0 + 1) * 72 + r] = (u16)(pv.x >> 16);
        VT[(d0 + 2) * 72 + r] = (u16)(pv.y); VT[(d0 + 3) * 72 + r] = (u16)(pv.y >> 16);
        VT[(d0 + 4) * 72 + r] = (u16)(pv.z); VT[(d0 + 5) * 72 + r] = (u16)(pv.z >> 16);
        VT[(d0 + 6) * 72 + r] = (u16)(pv.w); VT[(d0 + 7) * 72 + r] = (u16)(pv.w >> 16);
      }
    }
    f32x4 Sa[2][4];
#pragma unroll
    for (int rt = 0; rt < 2; ++rt)
#pragma unroll
      for (int ct = 0; ct < 4; ++ct) Sa[rt][ct] = f32x4{0.f, 0.f, 0.f, 0.f};
#pragma unroll
    for (int ks = 0; ks < 4; ++ks) {
      bf16x8 a0 = *(const bf16x8*)(qbase + (size_t)(wv * 32 + l15) * DH + ks * 32 + quad * 8);
      bf16x8 a1 = *(const bf16x8*)(qbase + (size_t)(wv * 32 + 16 + l15) * DH + ks * 32 + quad * 8);
#pragma unroll
      for (int ct = 0; ct < 4; ++ct) {
        bf16x8 bb = *(const bf16x8*)(khb + ((size_t)bh * T2 + kv0 + ct * 16 + l15) * DH + ks * 32 + quad * 8);
        Sa[0][ct] = __builtin_amdgcn_mfma_f32_16x16x32_bf16(a0, bb, Sa[0][ct], 0, 0, 0);
        Sa[1][ct] = __builtin_amdgcn_mfma_f32_16x16x32_bf16(a1, bb, Sa[1][ct], 0, 0, 0);
      }
    }
#pragma unroll
    for (int rt = 0; rt < 2; ++rt)
#pragma unroll
      for (int rg = 0; rg < 4; ++rg) {
        int row = wv * 32 + rt * 16 + quad * 4 + rg;
        int qp = t0 + row;
        float vals[4];
        float mx = -1e30f;
#pragma unroll
        for (int ct = 0; ct < 4; ++ct) {
          int kp = kv0 + ct * 16 + l15;
          float s = Sa[rt][ct][rg] * 0.08838834764831845f;
          bool ok = (kp <= qp) && (kp + 512 > qp);
          s = ok ? s : -1e30f;
          vals[ct] = s;
          mx = fmaxf(mx, s);
        }
#pragma unroll
        for (int sh = 1; sh < 16; sh <<= 1) mx = fmaxf(mx, __shfl_xor(mx, sh));
        float mold = mrow[rt][rg];
        float mnew = fmaxf(mold, mx);
        float alpha = __expf(mold - mnew);
        float rsum = 0.f;
        float pv_[4];
#pragma unroll
        for (int ct = 0; ct < 4; ++ct) {
          float p = (vals[ct] < -1e29f) ? 0.f : __expf(vals[ct] - mnew);
          pv_[ct] = p; rsum += p;
        }
#pragma unroll
        for (int sh = 1; sh < 16; sh <<= 1) rsum += __shfl_xor(rsum, sh);
        lrow[rt][rg] = lrow[rt][rg] * alpha + rsum;
        mrow[rt][rg] = mnew;
#pragma unroll
        for (int dt = 0; dt < 8; ++dt) Oa[rt][dt][rg] *= alpha;
#pragma unroll
        for (int ct = 0; ct < 4; ++ct) Pls[row * 72 + ct * 16 + l15] = f2bf(pv_[ct]);
      }
    __syncthreads();
#pragma unroll
    for (int ks = 0; ks < 2; ++ks) {
      bf16x8 a0 = *(const bf16x8*)(&Pls[(wv * 32 + l15) * 72 + ks * 32 + quad * 8]);
      bf16x8 a1 = *(const bf16x8*)(&Pls[(wv * 32 + 16 + l15) * 72 + ks * 32 + quad * 8]);
#pragma unroll
      for (int dt = 0; dt < 8; ++dt) {
        bf16x8 bb = *(const bf16x8*)(&VT[(dt * 16 + l15) * 72 + ks * 32 + quad * 8]);
        Oa[0][dt] = __builtin_amdgcn_mfma_f32_16x16x32_bf16(a0, bb, Oa[0][dt], 0, 0, 0);
        Oa[1][dt] = __builtin_amdgcn_mfma_f32_16x16x32_bf16(a1, bb, Oa[1][dt], 0, 0, 0);
      }
    }
  }
#pragma unroll
  for (int rt = 0; rt < 2; ++rt)
#pragma unroll
    for (int rg = 0; rg < 4; ++rg) {
      int row = wv * 32 + rt * 16 + quad * 4 + rg;
      float invl = 1.0f / lrow[rt][rg];
#pragma unroll
      for (int dt = 0; dt < 8; ++dt)
        yin[((size_t)b * T2 + t0 + row) * D2 + h * DH + dt * 16 + l15] = Oa[rt][dt][rg] * invl;
    }
}

// ---------------------------------------------------------------------------
// Kernel 3: slot-memory scan v16 — EXACTLY v14 (456us scan, 678.7us total,
// verified best) with ONE change: A24's two serial topk->RT chains fused
// into topk16_dual + joint gather issue.  Both index sets are computed
// before any memory op, so the sv-gather loads and the sk/vhb dot loads
// issue together and their LLC round trips overlap (2 exposed RTs -> 1);
// the interleaved bitonic networks also hide shuffle latency.
// (v11 bundled this with a harmful yin cached read; isolated here.)
// ---------------------------------------------------------------------------
struct ScanArgs {
  const u16* qhb; const u16* khb; const u16* vhb;
  float* yin; float* sk; float* sv; u16* skb; u16* khatb;
  u32* cnt; uint4* entries;
  u32* barcnt; u32* bargen; u32* ready;
  const float* sinit; const float* temp;
};

__device__ __forceinline__ void bh_barrier(u32* cnt, u32* gen, bool do_inv) {
  asm volatile("" ::: "memory");
  __syncthreads();           // vmcnt drain: this block's sc1 stores are LLC-visible
  if (threadIdx.x == 0) {
    u32 g = cload32(gen);
    u32 a = __hip_atomic_fetch_add(cnt, 1u, __ATOMIC_RELAXED, __HIP_MEMORY_SCOPE_AGENT);
    if ((a & 15u) == 15u) {
      cstore32(gen, g + 1u);
    } else {
      while (cload32(gen) == g) __builtin_amdgcn_s_sleep(2);
    }
    if (do_inv)
      __builtin_amdgcn_fence(__ATOMIC_ACQUIRE, "agent");  // one buffer_inv per chunk
  }
  __syncthreads();
  asm volatile("" ::: "memory");
}

// Dual top-16: two independent 512-element top-k+softmax sharing one bitonic
// network (interleaved for shuffle-latency hiding).  Correctness verified in
// v6 and v11 benches (both passed).
__device__ __forceinline__ void topk16_dual(
    const float* rp0, const float* rp1, int lane,
    volatile u64* cw0, volatile u64* cw1,
    float& p0_out, u32& i0_out, float& p1_out, u32& i1_out) {
  u32 mono[2][8];
#pragma unroll
  for (int j = 0; j < 8; ++j) {
    u32 u0 = __float_as_uint(rp0[j * 64 + lane]);
    u32 u1 = __float_as_uint(rp1[j * 64 + lane]);
    mono[0][j] = ((int)u0 < 0) ? ~u0 : (u0 | 0x80000000u);
    mono[1][j] = ((int)u1 < 0) ? ~u1 : (u1 | 0x80000000u);
  }
  u32 sv_[2];
#pragma unroll
  for (int s = 0; s < 2; ++s) {
    u32 mx = mono[s][0];
#pragma unroll
    for (int j = 1; j < 8; ++j) mx = max(mx, mono[s][j]);
    sv_[s] = mx;
  }
#pragma unroll
  for (int k = 2; k <= 64; k <<= 1) {
#pragma unroll
    for (int j = k >> 1; j > 0; j >>= 1) {
      bool km = (((lane & k) == 0) == ((lane & j) == 0));
#pragma unroll
      for (int s = 0; s < 2; ++s) {
        u32 o = (u32)__shfl_xor((int)sv_[s], j);
        u32 mn = min(sv_[s], o), mxx = max(sv_[s], o);
        sv_[s] = km ? mn : mxx;
      }
    }
  }
  u32 thr[2] = { (u32)__shfl((int)sv_[0], 48), (u32)__shfl((int)sv_[1], 48) };
  u32 base[2] = { 0u, 0u };
#pragma unroll
  for (int j = 0; j < 8; ++j) {
#pragma unroll
    for (int s = 0; s < 2; ++s) {
      bool pred = (mono[s][j] >= thr[s]);
      u64 mask = __ballot(pred);
      u32 pos = base[s] + (u32)__popcll(mask & ((1ull << lane) - 1ull));
      volatile u64* cw = s ? cw1 : cw0;
      if (pred && pos < 64u)
        cw[pos] = (((u64)mono[s][j]) << 32) | (u64)(0xFFFFFFFFu - (u32)(j * 64 + lane));
      base[s] += (u32)__popcll(mask);
    }
  }
  __threadfence_block();
  u64 key[2];
  {
    u32 c0 = base[0] < 64u ? base[0] : 64u;
    u32 c1 = base[1] < 64u ? base[1] : 64u;
    key[0] = ((u32)lane < c0) ? cw0[lane] : 0ull;
    key[1] = ((u32)lane < c1) ? cw1[lane] : 0ull;
  }
#pragma unroll
  for (int k = 2; k <= 64; k <<= 1) {
#pragma unroll
    for (int j = k >> 1; j > 0; j >>= 1) {
      bool km = (((lane & k) == 0) == ((lane & j) == 0));
#pragma unroll
      for (int s = 0; s < 2; ++s) {
        u64 o = __shfl_xor(key[s], j);
        u64 mn = key[s] < o ? key[s] : o;
        u64 mxx = key[s] < o ? o : key[s];
        key[s] = km ? mn : mxx;
      }
    }
  }
  float e[2], ssum[2]; u32 idx[2];
#pragma unroll
  for (int s = 0; s < 2; ++s) {
    u32 um = (u32)(key[s] >> 32);
    float val = __uint_as_float((um & 0x80000000u) ? (um & 0x7FFFFFFFu) : ~um);
    idx[s] = 0xFFFFFFFFu - (u32)(key[s] & 0xFFFFFFFFull);
    float mtop = __shfl(val, 63);
    e[s] = __expf(val - mtop);
    ssum[s] = e[s];
  }
#pragma unroll
  for (int sh = 1; sh < 16; sh <<= 1) {
    ssum[0] += __shfl_xor(ssum[0], sh);
    ssum[1] += __shfl_xor(ssum[1], sh);
  }
  p0_out = e[0] / ssum[0]; i0_out = idx[0];
  p1_out = e[1] / ssum[1]; i1_out = idx[1];
}

__global__ __launch_bounds__(512, 2) void scan_kernel(ScanArgs A) {
  const int tid = threadIdx.x;
  const int lane = tid & 63, wv = tid >> 6;
  const int quad = lane >> 4, l15 = lane & 15;
  // XCD-affinity mapping: a bh's 16 blocks share one XCD (L2 reuse of skb/sv/sk).
  const int xcd = blockIdx.x & 7;
  const int wi = blockIdx.x >> 3;           // 0..31 within XCD
  const int bh = xcd * 2 + (wi >> 4);       // 2 bh per XCD
  const int blk = wi & 15;                  // 16 blocks per bh
  const int b = bh >> 3, h = bh & 7;
  __shared__ float scores_r[8 * 520];
  __shared__ float scores_w[8 * 520];
  __shared__ u64 cand0[8][64];
  __shared__ u64 cand1[8][64];

  const float invtemp = 1.0f / A.temp[0];
  const float sc_r = 0.08838834764831845f * invtemp;

  // ---- init: this block's 32 slots (4 per wave) ----
#pragma unroll 1
  for (int i = 0; i < 4; ++i) {
    int s = blk * 32 + wv * 4 + i;
    float2 v2 = *(const float2*)(A.sinit + (size_t)s * 1024 + h * 128 + lane * 2);
    float ssq = v2.x * v2.x + v2.y * v2.y;
#pragma unroll
    for (int sh = 1; sh < 64; sh <<= 1) ssq += __shfl_xor(ssq, sh);
    float inv = 1.0f / (sqrtf(ssq) + 1e-6f);
    size_t off = ((size_t)bh * KSL + s) * DH + lane * 2;
    cstoref2(A.sk + off, make_float2(v2.x * inv, v2.y * inv));
    cstoref2(A.sv + off, v2);
    cstore32(A.skb + off, pack2(v2.x * inv, v2.y * inv));
    if (lane == 0) cstore32(&A.cnt[bh * KSL + s], 0u);
  }
  // ---- init: khat pre-pass — this wave's row for ALL 16 chunks (v14) ----
#pragma unroll 1
  for (int ci = 0; ci < NCH; ++ci) {
    int trow = ci * CH + blk * 8 + wv;
    u32 kraw = *(const u32*)(A.khb + ((size_t)bh * T2 + trow) * DH + lane * 2);
    float k0 = bf2f(kraw & 0xFFFFu), k1 = bf2f(kraw >> 16);
    float ssq = k0 * k0 + k1 * k1;
#pragma unroll
    for (int sh = 1; sh < 64; sh <<= 1) ssq += __shfl_xor(ssq, sh);
    float inv = 1.0f / (sqrtf(ssq) + 1e-6f);
    cstore32(A.khatb + ((size_t)bh * T2 + trow) * DH + lane * 2, pack2(k0 * inv, k1 * inv));
  }
  if (blk == 0 && tid == 0) { cstore32(A.barcnt + bh, 0u); cstore32(A.bargen + bh, 0u); }
  __syncthreads();  // drain vmcnt: init + khat stores LLC-visible before ready publish
  if (tid == 0) {
    cstore32(&A.ready[bh * 16 + blk], MAGIC);
    for (int i = 0; i < 16; ++i)
      while (cload32(&A.ready[bh * 16 + i]) != MAGIC) __builtin_amdgcn_s_sleep(2);
    __builtin_amdgcn_fence(__ATOMIC_ACQUIRE, "agent");  // drop stale lines before first reads
  }
  __syncthreads();

  u32* bcnt = A.barcnt + bh;
  u32* bgen = A.bargen + bh;

#pragma unroll 1
  for (int ci = 0; ci < NCH; ++ci) {
    const int t0base = ci * CH;
    const int c = blk * 8 + wv;          // this wave's chunk-row
    const int trow = t0base + c;
    // ---- A13: fused scores.  A-rows 0-7 = q, 8-15 = khat (khatb, immutable).
    {
      const u16* qbase = A.qhb + ((size_t)bh * T2 + t0base + blk * 8) * DH;
      const u16* hbase = A.khatb + ((size_t)bh * T2 + t0base + blk * 8) * DH;
      const u16* sbase = A.skb + (size_t)bh * KSL * DH;
      f32x4 acc[4];
#pragma unroll
      for (int ct = 0; ct < 4; ++ct) acc[ct] = f32x4{0.f, 0.f, 0.f, 0.f};
#pragma unroll
      for (int ks = 0; ks < 4; ++ks) {
        bf16x8 a;
        if (l15 < 8)
          a = *(const bf16x8*)(qbase + (size_t)l15 * DH + ks * 32 + quad * 8);
        else
          a = *(const bf16x8*)(hbase + (size_t)(l15 - 8) * DH + ks * 32 + quad * 8);
#pragma unroll
        for (int ct = 0; ct < 4; ++ct) {
          bf16x8 bb = *(const bf16x8*)(sbase + (size_t)(wv * 64 + ct * 16 + l15) * DH + ks * 32 + quad * 8);
          acc[ct] = __builtin_amdgcn_mfma_f32_16x16x32_bf16(a, bb, acc[ct], 0, 0, 0);
        }
      }
#pragma unroll
      for (int ct = 0; ct < 4; ++ct)
#pragma unroll
        for (int rg = 0; rg < 4; ++rg) {
          int m = quad * 4 + rg;
          int col = wv * 64 + ct * 16 + l15;
          if (m < 8) scores_r[m * 520 + col] = acc[ct][rg] * sc_r;
          else       scores_w[(m - 8) * 520 + col] = acc[ct][rg];
        }
    }
    __syncthreads();
    // ---- A24 (v16): ONE dual top-16, then joint gather issue ----
    {
      float p, wp; u32 sidx, widx;
      topk16_dual(&scores_r[wv * 520], &scores_w[wv * 520], lane,
                  cand0[wv], cand1[wv], p, sidx, wp, widx);
      // both index sets ready: sv-gather and sk/vhb-dot loads issue together,
      // their LLC round trips overlap.
      const int r = lane >> 2, g = lane & 3;   // 16 picks x 4 lanes
      float wr = __shfl(wp, 63 - r);
      u32 ir = (u32)__shfl((int)widx, 63 - r);
      const float* kb = A.sk + ((size_t)bh * KSL + ir) * DH + g * 32;
      const u16* vb = A.vhb + ((size_t)bh * T2 + trow) * DH + g * 32;

      float acc0 = 0.f, acc1 = 0.f;
      const float* svb = A.sv + (size_t)bh * KSL * DH;
      float part = 0.f;
#pragma unroll
      for (int u2 = 0; u2 < 4; ++u2) {
        uint4 vvp = *(const uint4*)(vb + u2 * 8);
        float4 k0 = *(const float4*)(kb + u2 * 8);
        float4 k1 = *(const float4*)(kb + u2 * 8 + 4);
        part += bf2f(vvp.x & 0xFFFFu) * k0.x + bf2f(vvp.x >> 16) * k0.y
              + bf2f(vvp.y & 0xFFFFu) * k0.z + bf2f(vvp.y >> 16) * k0.w
              + bf2f(vvp.z & 0xFFFFu) * k1.x + bf2f(vvp.z >> 16) * k1.y
              + bf2f(vvp.w & 0xFFFFu) * k1.z + bf2f(vvp.w >> 16) * k1.w;
      }
#pragma unroll
      for (int r2 = 0; r2 < 16; ++r2) {
        float pr = __shfl(p, 63 - r2);
        u32 ir2 = (u32)__shfl((int)sidx, 63 - r2);
        float2 vv = *(const float2*)(svb + (size_t)ir2 * DH + lane * 2);
        acc0 += pr * vv.x; acc1 += pr * vv.y;
      }
      {
        float* yp = A.yin + ((size_t)b * T2 + trow) * D2 + h * DH + lane * 2;
        float2 y0 = cloadf2(yp);
        cstoref2(yp, make_float2(y0.x + acc0, y0.y + acc1));
      }
      part += __shfl_xor(part, 1);
      part += __shfl_xor(part, 2);
      if (g == 0) {
        u32 pos = __hip_atomic_fetch_add(&A.cnt[bh * KSL + ir], 1u,
                                         __ATOMIC_RELAXED, __HIP_MEMORY_SCOPE_AGENT);
        if (pos < 128u) {
          u32* e = (u32*)(A.entries + ((size_t)bh * KSL + ir) * 128 + pos);
          cstore64(e, (u64)(u32)c | ((u64)__float_as_uint(wr) << 32));
          cstore32(e + 2, __float_as_uint(part));
        }
      }
    }
    bh_barrier(bcnt, bgen, false);   // bar1: NO inv (v12 audit)
    // ---- B: lane-parallel entry fetch + 16-deep batched gathers ----
    {
      u32 n4[4]; size_t soff4[4];
      uint4 eL0[4], eL1[4];
#pragma unroll
      for (int i = 0; i < 4; ++i) {
        soff4[i] = (size_t)bh * KSL + blk * 32 + wv * 4 + i;
        n4[i] = cload32(&A.cnt[soff4[i]]);
        const uint4* eb = A.entries + soff4[i] * 128;
        eL0[i] = eb[lane];         // cached, coalesced; fresh (audit)
        eL1[i] = eb[64 + lane];    // buffer always 128 entries -> no guard needed
      }
#pragma unroll
      for (int i = 0; i < 4; ++i) {
        size_t roff = soff4[i] * DH + lane * 2;
        float2 V = *(const float2*)(A.sv + roff);
        float2 Kr = *(const float2*)(A.sk + roff);
        u32 nd = n4[i] < 128u ? n4[i] : 128u;
        float dv0 = 0, dv1 = 0, dk0 = 0, dk1 = 0;
#pragma unroll 1
        for (u32 b2 = 0; b2 < nd; b2 += 16) {
          u32 m = nd - b2; if (m > 16u) m = 16u;
          // batch is entirely within eL0 (b2<64) or eL1 (b2>=64): 16 | 64.
          u32 sx = (b2 < 64u) ? eL0[i].x : eL1[i].x;
          u32 sy = (b2 < 64u) ? eL0[i].y : eL1[i].y;
          u32 sz = (b2 < 64u) ? eL0[i].z : eL1[i].z;
          u32 vr[16], hr[16];
#pragma unroll
          for (int j = 0; j < 16; ++j) if (j < (int)m) {
            u32 src = (b2 + (u32)j) & 63u;
            u32 c2 = (u32)__shfl((int)sx, (int)src);
            vr[j] = *(const u32*)(A.vhb + ((size_t)bh * T2 + t0base + c2) * DH + lane * 2);
            hr[j] = *(const u32*)(A.khatb + ((size_t)bh * T2 + t0base + c2) * DH + lane * 2);
          }
#pragma unroll
          for (int j = 0; j < 16; ++j) if (j < (int)m) {
            u32 src = (b2 + (u32)j) & 63u;
            float wpe = __uint_as_float((u32)__shfl((int)sy, (int)src));
            float pj = __uint_as_float((u32)__shfl((int)sz, (int)src));
            dv0 += wpe * (bf2f(vr[j] & 0xFFFFu) - pj * Kr.x);
            dv1 += wpe * (bf2f(vr[j] >> 16) - pj * Kr.y);
            dk0 += wpe * (bf2f(hr[j] & 0xFFFFu) - Kr.x);
            dk1 += wpe * (bf2f(hr[j] >> 16) - Kr.y);
          }
        }
        cstoref2(A.sv + roff, make_float2(0.99f * V.x + 0.1f * dv0, 0.99f * V.y + 0.1f * dv1));
        if (n4[i] > 0u) {
          float u0 = Kr.x + 0.1f * dk0, u1 = Kr.y + 0.1f * dk1;
          float ssq = u0 * u0 + u1 * u1;
#pragma unroll
          for (int sh = 1; sh < 64; sh <<= 1) ssq += __shfl_xor(ssq, sh);
          float inv = 1.0f / (sqrtf(ssq) + 1e-6f);
          u0 *= inv; u1 *= inv;
          cstoref2(A.sk + roff, make_float2(u0, u1));
          cstore32(A.skb + roff, pack2(u0, u1));
        }
        if (lane == 0) cstore32(&A.cnt[soff4[i]], 0u);
      }
    }
    bh_barrier(bcnt, bgen, true);    // bar2: the one inv per chunk
  }
}

// ---------------------------------------------------------------------------
// Kernel 4: output projection (unchanged, v14 form)
// ---------------------------------------------------------------------------
__global__ __launch_bounds__(256) void out_gemm(
    const float* __restrict__ yin, const float* __restrict__ w,
    const float* __restrict__ bias, float* __restrict__ out) {
  __shared__ u16 As[128 * 72];
  __shared__ u16 Bs[128 * 72];
  const int tid = threadIdx.x;
  const int lane = tid & 63, wv = tid >> 6;
  const int quad = lane >> 4, l15 = lane & 15;
  const int m0 = blockIdx.y * 128, n0 = blockIdx.x * 128;
  const int wr = wv >> 1, wc = wv & 1;
  f32x4 acc[4][4];
#pragma unroll
  for (int i = 0; i < 4; ++i)
#pragma unroll
    for (int j = 0; j < 4; ++j) acc[i][j] = f32x4{0.f, 0.f, 0.f, 0.f};
  const int f4c = tid & 15, r0 = tid >> 4;
  for (int kt = 0; kt < 16; ++kt) {
#pragma unroll
    for (int i = 0; i < 8; ++i) {
      int row = r0 + i * 16;
      float4 a = *(const float4*)(yin + (size_t)(m0 + row) * 1024 + kt * 64 + f4c * 4);
      float4 b = *(const float4*)(w + (size_t)(n0 + row) * 1024 + kt * 64 + f4c * 4);
      *(uint2*)(&As[row * 72 + f4c * 4]) = make_uint2(pack2(a.x, a.y), pack2(a.z, a.w));
      *(uint2*)(&Bs[row * 72 + f4c * 4]) = make_uint2(pack2(b.x, b.y), pack2(b.z, b.w));
    }
    __syncthreads();
#pragma unroll
    for (int ks = 0; ks < 2; ++ks) {
      bf16x8 af[4], bff[4];
#pragma unroll
      for (int rt = 0; rt < 4; ++rt)
        af[rt] = *(const bf16x8*)(&As[(wr * 64 + rt * 16 + l15) * 72 + ks * 32 + quad * 8]);
#pragma unroll
      for (int ct = 0; ct < 4; ++ct)
        bff[ct] = *(const bf16x8*)(&Bs[(wc * 64 + ct * 16 + l15) * 72 + ks * 32 + quad * 8]);
#pragma unroll
      for (int rt = 0; rt < 4; ++rt)
#pragma unroll
        for (int ct = 0; ct < 4; ++ct)
          acc[rt][ct] = __builtin_amdgcn_mfma_f32_16x16x32_bf16(af[rt], bff[ct], acc[rt][ct], 0, 0, 0);
    }
    __syncthreads();
  }
#pragma unroll
  for (int ct = 0; ct < 4; ++ct) {
    int n = n0 + wc * 64 + ct * 16 + l15;
    float bv = bias[n];
#pragma unroll
    for (int rt = 0; rt < 4; ++rt)
#pragma unroll
      for (int rg = 0; rg < 4; ++rg) {
        int m = m0 + wr * 64 + rt * 16 + quad * 4 + rg;
        out[(size_t)m * 1024 + n] = acc[rt][ct][rg] + bv;
      }
  }
}

// ---------------------------------------------------------------------------
extern "C" void kernel_launch(void* const* d_in, const int* in_sizes, int n_in,
                              void* d_out, int out_size, void* d_ws, size_t ws_size,
                              hipStream_t stream) {
  const float* x = (const float*)d_in[0];
  const float* Wqkv = (const float*)d_in[1];
  const float* bqkv = (const float*)d_in[2];
  const float* Wo = (const float*)d_in[3];
  const float* bo = (const float*)d_in[4];
  const float* Sinit = (const float*)d_in[5];
  const float* temp = (const float*)d_in[6];
  float* out = (float*)d_out;

  char* p = (char*)d_ws;
  auto take = [&](size_t bytes) { char* r = p; p += (bytes + 255) & ~(size_t)255; return r; };
  u16* qhb = (u16*)take((size_t)NBH * T2 * DH * 2);
  u16* khb = (u16*)take((size_t)NBH * T2 * DH * 2);
  u16* vhb = (u16*)take((size_t)NBH * T2 * DH * 2);
  float* yin = (float*)take((size_t)B2 * T2 * D2 * 4);
  float* sk = (float*)take((size_t)NBH * KSL * DH * 4);
  float* sv = (float*)take((size_t)NBH * KSL * DH * 4);
  u16* skb = (u16*)take((size_t)NBH * KSL * DH * 2);
  u16* khatb = (u16*)take((size_t)NBH * T2 * DH * 2);   // full T2 (v14)
  u32* cnt = (u32*)take((size_t)NBH * KSL * 4);
  uint4* entries = (uint4*)take((size_t)NBH * KSL * 128 * 16);
  u32* barcnt = (u32*)take(64 * 4);
  u32* bargen = (u32*)take(64 * 4);
  u32* ready = (u32*)take(NBH * 16 * 4);

  hipLaunchKernelGGL(qkv_gemm, dim3(24, 32), dim3(256), 0, stream, x, Wqkv, bqkv, qhb, khb, vhb);
  hipLaunchKernelGGL(attn_kernel, dim3(16, 16), dim3(256), 0, stream, qhb, khb, vhb, yin);
  ScanArgs sa{qhb, khb, vhb, yin, sk, sv, skb, khatb, cnt, entries, barcnt, bargen, ready, Sinit, temp};
  hipLaunchKernelGGL(scan_kernel, dim3(256), dim3(512), 0, stream, sa);
  hipLaunchKernelGGL(out_gemm, dim3(8, 32), dim3(256), 0, stream, yin, Wo, bo, out);
}